// Round 4
// baseline (517.867 us; speedup 1.0000x reference)
//
#include <hip/hip_runtime.h>
#include <hip/hip_bf16.h>
#include <cstdint>
#include <cstddef>

#define NN     8192
#define INF_   256
#define OUTF   128
#define ALPHA  0.2f
#define LOG2E  1.4426950408889634f
#define JSPLIT 4
#define CHUNK  (NN / JSPLIT)   // 2048

typedef __bf16 bf16;
typedef unsigned int u32;
typedef __attribute__((ext_vector_type(8))) __bf16 bf16x8;
typedef __attribute__((ext_vector_type(4))) float f32x4;
typedef __attribute__((ext_vector_type(4))) unsigned int u32x4;
typedef __attribute__((ext_vector_type(8))) unsigned short u16x8;
typedef __attribute__((ext_vector_type(4))) unsigned short u16x4;

// ---------------------------------------------------------------------------
// Dtype detector: read x's first 2048 uint16s as bf16. fp32 storage -> words
// are fp32 mantissa fragments -> huge exponents; bf16 storage -> N(0,1).
// flag = 1 -> tensors are fp32; 0 -> bf16.  (R2/R3: flag=1 confirmed.)
// ---------------------------------------------------------------------------
__global__ void gat_detect(const unsigned short* __restrict__ xr, int* __restrict__ flag)
{
    const int lane = threadIdx.x & 63;
    float m = 0.f;
    #pragma unroll
    for (int t = 0; t < 32; ++t) {
        const unsigned short u = xr[lane * 32 + t];
        const float v = fabsf((float)__builtin_bit_cast(bf16, u));
        if (v == v) m = fmaxf(m, v);
    }
    #pragma unroll
    for (int d = 1; d < 64; d <<= 1) m = fmaxf(m, __shfl_xor(m, d));
    if (lane == 0) *flag = (m > 100.f) ? 1 : 0;
}

// dtype-generic helpers ------------------------------------------------------
static __device__ __forceinline__ bf16  loadS(const bf16* p)  { return *p; }
static __device__ __forceinline__ bf16  loadS(const float* p) { return (bf16)*p; }
static __device__ __forceinline__ float loadF(const bf16* p)  { return (float)*p; }
static __device__ __forceinline__ float loadF(const float* p) { return *p; }
static __device__ __forceinline__ void load4(const float* p, bf16* d) {
    const f32x4 v = *(const f32x4*)p;
    #pragma unroll
    for (int t = 0; t < 4; ++t) d[t] = (bf16)v[t];
}
static __device__ __forceinline__ void load4(const bf16* p, bf16* d) {
    *(u16x4*)d = *(const u16x4*)p;
}

// ---------------------------------------------------------------------------
// trans transpose: TT[n][k] = bf16(trans[k][n]).
// ---------------------------------------------------------------------------
template <typename T, int WANT>
__global__ void gat_tt(const T* __restrict__ trans, const int* __restrict__ flag,
                       bf16* __restrict__ TT)
{
    if (*flag != WANT) return;
    const int n = blockIdx.x;      // 0..127
    const int k = threadIdx.x;     // 0..255
    TT[n * INF_ + k] = loadS(trans + k * OUTF + n);
}

// ---------------------------------------------------------------------------
// adj bitpack: maskG[row][jw] bit (j&31) = (adj[row][j] != 0).
// Perfectly coalesced dword stream + ballot. This kernel IS the HBM floor
// (256 MB read once).
// ---------------------------------------------------------------------------
__global__ __launch_bounds__(256)
void gat_pack(const int* __restrict__ adj, u32* __restrict__ maskG)
{
    const int tid  = threadIdx.x;
    const int wave = tid >> 6;
    const int lane = tid & 63;
    const int row  = blockIdx.x;
    const int* ap = adj + (size_t)row * NN + wave * 2048;   // 32 units of 64 j
    u32*       mp = maskG + (size_t)row * (NN / 32) + wave * 64;

    int v[32];
    #pragma unroll
    for (int u = 0; u < 32; ++u) v[u] = ap[u * 64 + lane];
    #pragma unroll
    for (int u = 0; u < 32; ++u) {
        const unsigned long long b = __ballot(v[u] != 0);
        if (lane == 0) *(unsigned long long*)(mp + u * 2) = b;
    }
}

// ---------------------------------------------------------------------------
// Projection: h = x @ trans via LDS-staged MFMA. Outputs:
//   HTt tiled: HTt[i>>5][n][i&31]  (attn b-frag loads become contiguous 1KB)
//   e1c/e2c (pre-scaled by log2e)
// Block = 32 rows; wave w: rowhalf w&1, feathalf w>>1 (4 16x16 n-tiles each).
// ---------------------------------------------------------------------------
template <typename T, int WANT>
__global__ __launch_bounds__(256, 1)
void gat_proj_t(const T* __restrict__ x, const bf16* __restrict__ TT,
                const T* __restrict__ aw, const int* __restrict__ flag,
                bf16* __restrict__ HTt, float* __restrict__ e1c, float* __restrict__ e2c)
{
    if (*flag != WANT) return;

    __shared__ bf16  xs[32][264];    // 256 cols + 8 pad (16B-aligned stride)
    __shared__ bf16  TTs[128][264];
    __shared__ float hl[32][129];

    const int tid  = threadIdx.x;
    const int wave = tid >> 6;
    const int lane = tid & 63;
    const int m    = lane & 15;
    const int q    = lane >> 4;
    const int i0   = blockIdx.x * 32;

    // stage x (linear, coalesced 1KB/wave-instr), cvt to bf16
    #pragma unroll
    for (int it = 0; it < 8; ++it) {
        const int e = it * 1024 + tid * 4;        // flat elem in 32x256 slice
        bf16 tmp[4];
        load4(x + (size_t)i0 * INF_ + e, tmp);
        *(u16x4*)&xs[e >> 8][e & 255] = *(u16x4*)tmp;
    }
    // stage TT (linear, coalesced)
    #pragma unroll
    for (int it = 0; it < 16; ++it) {
        const int e = it * 2048 + tid * 8;        // flat elem in 128x256
        *(u16x8*)&TTs[e >> 8][e & 255] = *(const u16x8*)(TT + e);
    }
    __syncthreads();

    const int rh = wave & 1, fh = wave >> 1;
    f32x4 acc[4] = {};
    #pragma unroll
    for (int ks = 0; ks < INF_; ks += 32) {
        const bf16x8 a = *(const bf16x8*)&xs[rh * 16 + m][ks + q * 8];
        #pragma unroll
        for (int tn = 0; tn < 4; ++tn) {
            const bf16x8 b = *(const bf16x8*)&TTs[fh * 64 + tn * 16 + m][ks + q * 8];
            acc[tn] = __builtin_amdgcn_mfma_f32_16x16x32_bf16(a, b, acc[tn], 0, 0, 0);
        }
    }

    // C/D layout: col = lane&15, row = q*4 + reg
    #pragma unroll
    for (int tn = 0; tn < 4; ++tn)
        #pragma unroll
        for (int r = 0; r < 4; ++r)
            hl[rh * 16 + q * 4 + r][fh * 64 + tn * 16 + m] = acc[tn][r];
    __syncthreads();

    {   // e1/e2: 8 threads per row, 16 cols each, reduce over 8 lanes
        const int r = tid >> 3, seg = tid & 7;
        float s1 = 0.f, s2 = 0.f;
        #pragma unroll
        for (int u = 0; u < 16; ++u) {
            const float hv = hl[r][seg * 16 + u];
            s1 += hv * loadF(aw + seg * 16 + u);
            s2 += hv * loadF(aw + OUTF + seg * 16 + u);
        }
        #pragma unroll
        for (int d = 1; d < 8; d <<= 1) {
            s1 += __shfl_xor(s1, d);
            s2 += __shfl_xor(s2, d);
        }
        if (seg == 0) {
            e1c[i0 + r] = s1 * LOG2E;
            e2c[i0 + r] = s2 * LOG2E;
        }
    }

    {   // HTt tiled write: thread t -> n = t>>1, ih = t&1; 2x16B contig stores
        const int n = tid >> 1, ih = tid & 1;
        u16x8 p0, p1;
        #pragma unroll
        for (int v = 0; v < 8; ++v) {
            p0[v] = __builtin_bit_cast(unsigned short, (bf16)hl[ih * 16 + v][n]);
            p1[v] = __builtin_bit_cast(unsigned short, (bf16)hl[ih * 16 + 8 + v][n]);
        }
        bf16* base = HTt + (size_t)blockIdx.x * 4096 + n * 32 + ih * 16;
        *(u16x8*)base       = p0;
        *(u16x8*)(base + 8) = p1;
    }
}

// ---------------------------------------------------------------------------
// Fused masked-softmax-attention partials. No LDS, no barriers, no atomics.
// Block = 4 waves x 16-row i-tiles (64 rows), one 2048-j chunk, all 128 feats.
// All loads coalesced: mask 16B/lane per 128 j (L2-hot 8MB), b-frags 1KB/wave
// contiguous from tiled HTt (L1/L2-hot 2MB). Hand-pipelined prefetch.
// jc = bid&3 -> each XCD touches one HTt/mask j-slice only.
// ---------------------------------------------------------------------------
__global__ __launch_bounds__(256, 2)
void gat_attn(const u32* __restrict__ maskG, const bf16* __restrict__ HTt,
              const float* __restrict__ e1c, const float* __restrict__ e2c,
              float* __restrict__ numP, float* __restrict__ denP)
{
    const int tid  = threadIdx.x;
    const int wave = tid >> 6;
    const int lane = tid & 63;
    const int m    = lane & 15;
    const int q    = lane >> 4;
    const int jc   = blockIdx.x & 3;
    const int ig   = blockIdx.x >> 2;
    const int rbase = ig * 64 + wave * 16;
    const int row   = rbase + m;
    const int j0    = jc * CHUNK;

    const float e1 = e1c[row];
    const u32*   pm = maskG + (size_t)row * (NN / 32) + (j0 >> 5);
    const float* pe = e2c + j0 + q * 8;
    const bf16*  pb = HTt + (size_t)(j0 >> 5) * 4096 + m * 32 + q * 8;

    f32x4 acc[8] = {};
    float rs = 0.f;

    // prologue prefetch (step 0 / window 0)
    u32x4 mw = *(const u32x4*)pm;
    bf16x8 bc[8];
    #pragma unroll
    for (int t = 0; t < 8; ++t)
        bc[t] = __builtin_bit_cast(bf16x8, *(const u32x4*)(pb + t * 512));
    f32x4 e2a = *(const f32x4*)pe;
    f32x4 e2b = *(const f32x4*)(pe + 4);

    for (int jw = 0; jw < CHUNK; jw += 128) {
        const int jwn = (jw + 128 < CHUNK) ? jw + 128 : jw;    // clamped
        const u32x4 mwn = *(const u32x4*)(pm + (jwn >> 5));
        #pragma unroll
        for (int s = 0; s < 4; ++s) {
            const int step = jw + s * 32;
            int nstep = step + 32;
            if (nstep > CHUNK - 32) nstep = CHUNK - 32;        // clamped
            // prefetch next step
            bf16x8 bn[8];
            const bf16* pbn = pb + (size_t)(nstep >> 5) * 4096;
            #pragma unroll
            for (int t = 0; t < 8; ++t)
                bn[t] = __builtin_bit_cast(bf16x8, *(const u32x4*)(pbn + t * 512));
            const f32x4 e2an = *(const f32x4*)(pe + nstep);
            const f32x4 e2bn = *(const f32x4*)(pe + nstep + 4);

            // build P fragment from mask bits (leaky-relu in log2 domain)
            const u32 w = mw[s];
            bf16x8 af;
            #pragma unroll
            for (int t = 0; t < 4; ++t) {
                float sv = e1 + e2a[t];
                sv = fmaxf(sv, ALPHA * sv);
                const float p = ((w >> (q * 8 + t)) & 1u) ? __builtin_amdgcn_exp2f(sv) : 0.f;
                rs += p;
                af[t] = (bf16)p;
            }
            #pragma unroll
            for (int t = 0; t < 4; ++t) {
                float sv = e1 + e2b[t];
                sv = fmaxf(sv, ALPHA * sv);
                const float p = ((w >> (q * 8 + 4 + t)) & 1u) ? __builtin_amdgcn_exp2f(sv) : 0.f;
                rs += p;
                af[4 + t] = (bf16)p;
            }

            #pragma unroll
            for (int t = 0; t < 8; ++t)
                acc[t] = __builtin_amdgcn_mfma_f32_16x16x32_bf16(af, bc[t], acc[t], 0, 0, 0);
            #pragma unroll
            for (int t = 0; t < 8; ++t) bc[t] = bn[t];
            e2a = e2an; e2b = e2bn;
        }
        mw = mwn;
    }

    // row-sum: lanes {m, m+16, m+32, m+48} hold the 4 q-slices of row m
    rs += __shfl_xor(rs, 16);
    rs += __shfl_xor(rs, 32);
    if (lane < 16) denP[(size_t)jc * NN + rbase + m] = rs;

    // C/D layout: col = lane&15, row = q*4 + r  -> unique partial slot (no atomics)
    #pragma unroll
    for (int t = 0; t < 8; ++t)
        #pragma unroll
        for (int r = 0; r < 4; ++r)
            numP[((size_t)jc * NN + rbase + q * 4 + r) * OUTF + t * 16 + m] = acc[t][r];
}

// ---------------------------------------------------------------------------
// Finalize: out = elu( (sum_s numP) / (sum_s denP) )
// ---------------------------------------------------------------------------
__global__ __launch_bounds__(256)
void gat_fin(const float* __restrict__ numP, const float* __restrict__ denP,
             const int* __restrict__ flag, void* __restrict__ outv)
{
    const int g  = blockIdx.x * 256 + threadIdx.x;   // one thread per 4 elems
    const int i  = g >> 5;
    const int c4 = g & 31;
    float d = 0.f;
    f32x4 v = {0.f, 0.f, 0.f, 0.f};
    #pragma unroll
    for (int s = 0; s < JSPLIT; ++s) {
        d += denP[(size_t)s * NN + i];
        const f32x4 u = *(const f32x4*)(numP + ((size_t)s * NN + i) * OUTF + c4 * 4);
        #pragma unroll
        for (int t = 0; t < 4; ++t) v[t] += u[t];
    }
    #pragma unroll
    for (int t = 0; t < 4; ++t) {
        const float u = v[t] / d;
        v[t] = (u > 0.f) ? u : __builtin_amdgcn_exp2f(u * LOG2E) - 1.f;  // elu
    }
    const size_t off = (size_t)i * OUTF + c4 * 4;
    if (*flag) {
        *(f32x4*)((float*)outv + off) = v;
    } else {
        u16x4 pk;
        #pragma unroll
        for (int t = 0; t < 4; ++t)
            pk[t] = __builtin_bit_cast(unsigned short, (bf16)v[t]);
        *(u16x4*)((__hip_bfloat16*)outv + off) = pk;
    }
}

// ---------------------------------------------------------------------------
extern "C" void kernel_launch(void* const* d_in, const int* in_sizes, int n_in,
                              void* d_out, int out_size, void* d_ws, size_t ws_size,
                              hipStream_t stream)
{
    const int* adj = (const int*)d_in[1];

    // ws layout (bytes):
    // HTt 2MB | e1c 32KB | e2c 32KB | flag 256B | TT 64KB | maskG 8MB
    // | numP 16MB | denP 128KB   (~27.3 MB total)
    char* w = (char*)d_ws;
    bf16*  HTt  = (bf16*)w;   w += (size_t)OUTF * NN * 2;
    float* e1c  = (float*)w;  w += NN * 4;
    float* e2c  = (float*)w;  w += NN * 4;
    int*   flag = (int*)w;    w += 256;
    bf16*  TT   = (bf16*)w;   w += (size_t)OUTF * INF_ * 2;
    u32*   maskG= (u32*)w;    w += (size_t)NN * (NN / 32) * 4;
    float* numP = (float*)w;  w += (size_t)JSPLIT * NN * OUTF * 4;
    float* denP = (float*)w;

    gat_detect<<<1, 64, 0, stream>>>((const unsigned short*)d_in[0], flag);

    gat_tt<float, 1><<<OUTF, INF_, 0, stream>>>((const float*)d_in[2], flag, TT);
    gat_tt<bf16, 0><<<OUTF, INF_, 0, stream>>>((const bf16*)d_in[2], flag, TT);

    gat_pack<<<NN, 256, 0, stream>>>(adj, maskG);

    gat_proj_t<float, 1><<<NN / 32, 256, 0, stream>>>(
        (const float*)d_in[0], TT, (const float*)d_in[3], flag, HTt, e1c, e2c);
    gat_proj_t<bf16, 0><<<NN / 32, 256, 0, stream>>>(
        (const bf16*)d_in[0], TT, (const bf16*)d_in[3], flag, HTt, e1c, e2c);

    gat_attn<<<(NN / 64) * JSPLIT, 256, 0, stream>>>(maskG, HTt, e1c, e2c, numP, denP);

    gat_fin<<<NN * OUTF / 4 / 256, 256, 0, stream>>>(numP, denP, flag, d_out);
}